// Round 1
// 435.474 us; speedup vs baseline: 1.0656x; 1.0656x over previous
//
#include <hip/hip_runtime.h>
#include <math.h>

#define BATCH 512
#define SEQ   200
#define TOK   10
#define EMB   25
#define HID   64
#define G3    192   // 3*HID

__device__ __forceinline__ float fast_sigmoid(float t) {
    float e = __expf(-t);
    return __builtin_amdgcn_rcpf(1.f + e);
}
__device__ __forceinline__ float fast_tanh(float t) {
    float e2 = __expf(2.f * t);
    return 1.f - 2.f * __builtin_amdgcn_rcpf(e2 + 1.f);
}

// Barrier that orders LDS producer->consumer WITHOUT draining vmcnt:
// writer-side ds ops complete (lgkmcnt(0)), then s_barrier. The global
// out-store stays fire-and-forget (no vmcnt(0) on the critical path).
#define LDS_BARRIER() do {                                   \
    asm volatile("s_waitcnt lgkmcnt(0)" ::: "memory");       \
    __builtin_amdgcn_s_barrier();                            \
    asm volatile("" ::: "memory");                           \
} while (0)

// ---------------------------------------------------------------------------
// Kernel 1: masked-mean embedding bag + step mask (unchanged)
// ---------------------------------------------------------------------------
__global__ __launch_bounds__(256) void emb_mean_kernel(
    const int* __restrict__ ids_g, const float* __restrict__ emb,
    float* __restrict__ x, float* __restrict__ mask)
{
    int grp  = blockIdx.x * 8 + (threadIdx.x >> 5);
    int lane = threadIdx.x & 31;
    if (grp >= BATCH * SEQ) return;
    const int* ids = ids_g + (size_t)grp * TOK;
    float acc = 0.f;
    int cnt = 0;
    #pragma unroll
    for (int t = 0; t < TOK; t++) {
        int id = ids[t];
        if (id != 0) {
            cnt++;
            if (lane < EMB) acc += emb[(size_t)id * EMB + lane];
        }
    }
    if (lane < EMB)
        x[(size_t)grp * EMB + lane] = cnt ? acc / (float)cnt : 0.f;
    if (lane == 0)
        mask[grp] = (ids[0] != 0) ? 1.f : 0.f;
}

// ---------------------------------------------------------------------------
// Kernel 2: GRU scan — THREE WAVES per (batch, direction), gate-split.
//   wave 0 -> z gate, wave 1 -> r gate, wave 2 -> h gate + combine.
// Each lane holds ONE gate column of U (64 f32) + W (25 f32) + biases:
// ~95 weight floats/lane -> fits in VGPRs (the 1-wave version needed 267
// floats and spilled at VGPR_Count=176, stalling every step on reloads).
// Per step:
//   all waves : rec-dot (broadcast hs reads, register U column)
//   w0/w1     : sigmoid -> zs/rs in LDS
//   LDS_BARRIER (A)
//   w2        : hh = tanh(ph + r*ah); hn = z*h+(1-z)*hh; mask; hs[j]=hn;
//               out store (fire-and-forget, never vmcnt-drained in-loop)
//   all waves : x-dot for NEXT step (h-independent -> fills the idle slot)
//   LDS_BARRIER (B)
// ---------------------------------------------------------------------------
__global__ __launch_bounds__(192, 3) void gru_kernel(
    const float* __restrict__ xg, const float* __restrict__ maskg,
    const float* __restrict__ W_f, const float* __restrict__ U_f, const float* __restrict__ b_f,
    const float* __restrict__ W_b, const float* __restrict__ U_b, const float* __restrict__ b_b,
    float* __restrict__ outg, float* __restrict__ hT)
{
    const int bidx = blockIdx.x;
    const int dir  = bidx >> 9;        // 0 = forward, 1 = backward
    const int b    = bidx & 511;
    const int tid  = threadIdx.x;
    const int w    = tid >> 6;         // gate index: 0=z, 1=r, 2=h
    const int j    = tid & 63;         // hidden column

    const float* W    = dir ? W_b : W_f;
    const float* U    = dir ? U_b : U_f;
    const float* bias = dir ? b_b : b_f;

    const int col = w * HID + j;

    // per-lane weight column for THIS gate only
    float Ug[HID];
    #pragma unroll
    for (int k = 0; k < HID; k++) Ug[k] = U[k * G3 + col];
    float Wg[EMB];
    #pragma unroll
    for (int e = 0; e < EMB; e++) Wg[e] = W[e * G3 + col];
    const float bx = bias[col];        // input-projection bias
    const float br = bias[G3 + col];   // recurrent bias

    __shared__ float xs[SEQ * EMB];    // 20 KB: this batch's x rows
    __shared__ float ms[SEQ];
    __shared__ float hs[HID];
    __shared__ float zs[HID];
    __shared__ float rs[HID];

    // cooperative staging (vectorized; 5000 floats = 1250 float4)
    {
        const float4* xrow4 = (const float4*)(xg + (size_t)b * (SEQ * EMB));
        float4* xs4 = (float4*)xs;
        for (int i = tid; i < (SEQ * EMB) / 4; i += 192) xs4[i] = xrow4[i];
        for (int i = tid; i < SEQ; i += 192) ms[i] = maskg[(size_t)b * SEQ + i];
        if (tid < HID) hs[tid] = 0.f;
    }
    __syncthreads();   // staging barrier (vmcnt drain fine, once)

    float h = 0.f;     // running hidden state, live only in wave 2
    float* obase = outg + (size_t)b * SEQ * (2 * HID) + dir * HID + j;

    // software-pipelined x-projection for step 0
    float p;
    {
        const int s0 = dir ? (SEQ - 1) : 0;
        const float* xr = xs + s0 * EMB;
        float q0 = bx, q1 = 0.f;
        #pragma unroll
        for (int e = 0; e + 1 < EMB; e += 2) {
            q0 = fmaf(xr[e],     Wg[e],     q0);
            q1 = fmaf(xr[e + 1], Wg[e + 1], q1);
        }
        q0 = fmaf(xr[EMB - 1], Wg[EMB - 1], q0);
        p = q0 + q1;
    }

    for (int step = 0; step < SEQ; step++) {
        const int s = dir ? (SEQ - 1 - step) : step;

        // recurrent dot: a = br + hs . Ug   (4 accumulators -> issue-bound)
        float a0 = br, a1 = 0.f, a2 = 0.f, a3 = 0.f;
        #pragma unroll
        for (int k = 0; k < HID; k += 4) {
            a0 = fmaf(hs[k],     Ug[k],     a0);
            a1 = fmaf(hs[k + 1], Ug[k + 1], a1);
            a2 = fmaf(hs[k + 2], Ug[k + 2], a2);
            a3 = fmaf(hs[k + 3], Ug[k + 3], a3);
        }
        const float a = (a0 + a1) + (a2 + a3);

        if (w == 0)      zs[j] = fast_sigmoid(p + a);
        else if (w == 1) rs[j] = fast_sigmoid(p + a);

        LDS_BARRIER();   // A: zs/rs visible to wave 2

        if (w == 2) {
            float r  = rs[j];
            float z  = zs[j];
            float hh = fast_tanh(p + r * a);        // p = xh-part, a = rec-part
            float hn = z * h + (1.f - z) * hh;
            hn = (ms[s] != 0.f) ? hn : h;
            h = hn;
            hs[j] = hn;
            obase[(size_t)s * (2 * HID)] = hn;      // fire-and-forget
        }

        // x-projection for the NEXT step (h-independent): overlaps wave-2's
        // combine latency and waves 0/1's barrier wait.
        {
            const int sn  = dir ? (SEQ - 2 - step) : (step + 1);
            const int snc = (step + 1 < SEQ) ? sn : s;   // clamp (value unused on last iter)
            const float* xr = xs + snc * EMB;
            float q0 = bx, q1 = 0.f;
            #pragma unroll
            for (int e = 0; e + 1 < EMB; e += 2) {
                q0 = fmaf(xr[e],     Wg[e],     q0);
                q1 = fmaf(xr[e + 1], Wg[e + 1], q1);
            }
            q0 = fmaf(xr[EMB - 1], Wg[EMB - 1], q0);
            p = q0 + q1;
        }

        LDS_BARRIER();   // B: new hs visible to all waves
    }
    if (w == 2 && dir == 0) hT[(size_t)b * HID + j] = h;
}

// ---------------------------------------------------------------------------
// Kernel 3: attention pooling (unchanged). One block (256 thr) per batch.
// ---------------------------------------------------------------------------
__global__ __launch_bounds__(256) void attn_kernel(
    const float* __restrict__ outg, const float* __restrict__ maskg,
    const float* __restrict__ hT,
    const float* __restrict__ W_k, const float* __restrict__ b_k,
    const float* __restrict__ W_q, const float* __restrict__ b_q,
    const float* __restrict__ W_e, const float* __restrict__ b_e,
    float* __restrict__ ctx)
{
    const int b   = blockIdx.x;
    const int tid = threadIdx.x;

    __shared__ float Wks[2 * HID * HID];   // 128x64 = 32 KB
    __shared__ float qs[HID];
    __shared__ float es[SEQ];

    for (int i = tid; i < 2 * HID * HID; i += 256) Wks[i] = W_k[i];
    if (tid < HID) {
        float q = b_q[tid];
        const float* hrow = hT + (size_t)b * HID;
        #pragma unroll 8
        for (int i = 0; i < HID; i++) q = fmaf(hrow[i], W_q[i * HID + tid], q);
        qs[tid] = q;
    }
    __syncthreads();

    const int wave = tid >> 6;
    const int lane = tid & 63;
    const float bk = b_k[lane];
    const float we = W_e[lane];
    const float be = b_e[0];

    // phase 1: scores e[s]; each wave takes every 4th s
    for (int s = wave; s < SEQ; s += 4) {
        const float* orow = outg + ((size_t)b * SEQ + s) * (2 * HID);
        float a0 = 0.f, a1 = 0.f, a2 = 0.f, a3 = 0.f;
        #pragma unroll
        for (int i = 0; i < 2 * HID; i += 4) {
            a0 = fmaf(orow[i + 0], Wks[(i + 0) * HID + lane], a0);
            a1 = fmaf(orow[i + 1], Wks[(i + 1) * HID + lane], a1);
            a2 = fmaf(orow[i + 2], Wks[(i + 2) * HID + lane], a2);
            a3 = fmaf(orow[i + 3], Wks[(i + 3) * HID + lane], a3);
        }
        float t = tanhf(((a0 + a1) + (a2 + a3)) + bk + qs[lane]) * we;
        #pragma unroll
        for (int off = 32; off > 0; off >>= 1) t += __shfl_down(t, off);
        if (lane == 0) {
            float pen = (maskg[(size_t)b * SEQ + s] != 0.f) ? 0.f : -1e9f;
            es[s] = t + be + pen;
        }
    }
    __syncthreads();

    // phase 2: softmax over the 200 scores (single wave)
    if (tid < 64) {
        float mx = -1e30f;
        for (int s2 = tid; s2 < SEQ; s2 += 64) mx = fmaxf(mx, es[s2]);
        #pragma unroll
        for (int off = 32; off > 0; off >>= 1) mx = fmaxf(mx, __shfl_xor(mx, off));
        float sum = 0.f;
        for (int s2 = tid; s2 < SEQ; s2 += 64) {
            float w = expf(es[s2] - mx);
            es[s2] = w;
            sum += w;
        }
        #pragma unroll
        for (int off = 32; off > 0; off >>= 1) sum += __shfl_xor(sum, off);
        float inv = 1.f / sum;
        for (int s2 = tid; s2 < SEQ; s2 += 64) es[s2] *= inv;
    }
    __syncthreads();

    // phase 3: context[j] = sum_s w[s] * out[b,s,j]
    if (tid < 2 * HID) {
        const int jj = tid;
        float a0 = 0.f, a1 = 0.f;
        for (int s2 = 0; s2 < SEQ; s2 += 2) {
            a0 = fmaf(es[s2],     outg[((size_t)b * SEQ + s2)     * (2 * HID) + jj], a0);
            a1 = fmaf(es[s2 + 1], outg[((size_t)b * SEQ + s2 + 1) * (2 * HID) + jj], a1);
        }
        ctx[(size_t)b * (2 * HID) + jj] = a0 + a1;
    }
}

// ---------------------------------------------------------------------------
extern "C" void kernel_launch(void* const* d_in, const int* in_sizes, int n_in,
                              void* d_out, int out_size, void* d_ws, size_t ws_size,
                              hipStream_t stream) {
    const int*   ids = (const int*)  d_in[0];
    const float* emb = (const float*)d_in[1];
    const float* W_f = (const float*)d_in[2];
    const float* U_f = (const float*)d_in[3];
    const float* b_f = (const float*)d_in[4];
    const float* W_b = (const float*)d_in[5];
    const float* U_b = (const float*)d_in[6];
    const float* b_b = (const float*)d_in[7];
    const float* W_k = (const float*)d_in[8];
    const float* b_k = (const float*)d_in[9];
    const float* W_q = (const float*)d_in[10];
    const float* b_q = (const float*)d_in[11];
    const float* W_e = (const float*)d_in[12];
    const float* b_e = (const float*)d_in[13];

    float* ws   = (float*)d_ws;
    // workspace layout (floats):
    //   x    : [0, 2'560'000)                 (B*S*E)
    //   mask : [2'560'000, 2'662'400)         (B*S)
    //   out  : [2'662'400, 15'769'600)        (B*S*2H)
    //   hT   : [15'769'600, 15'802'368)       (B*H)
    float* x    = ws;
    float* mask = ws + 2560000;
    float* out  = ws + 2662400;
    float* hT   = ws + 15769600;

    emb_mean_kernel<<<(BATCH * SEQ) / 8, 256, 0, stream>>>(ids, emb, x, mask);
    gru_kernel<<<1024, 192, 0, stream>>>(x, mask, W_f, U_f, b_f,
                                         W_b, U_b, b_b, out, hT);
    attn_kernel<<<BATCH, 256, 0, stream>>>(out, mask, hT, W_k, b_k,
                                           W_q, b_q, W_e, b_e, (float*)d_out);
}

// Round 2
// 431.151 us; speedup vs baseline: 1.0763x; 1.0100x over previous
//
#include <hip/hip_runtime.h>
#include <math.h>

#define BATCH 512
#define SEQ   200
#define TOK   10
#define EMB   25
#define XPAD  28    // xs row stride (floats): 112 B, 16B-aligned rows
#define HID   64
#define G3    192   // 3*HID

__device__ __forceinline__ float fast_sigmoid(float t) {
    float e = __expf(-t);
    return __builtin_amdgcn_rcpf(1.f + e);
}
__device__ __forceinline__ float fast_tanh(float t) {
    float e2 = __expf(2.f * t);
    return 1.f - 2.f * __builtin_amdgcn_rcpf(e2 + 1.f);
}

// Barrier that orders LDS producer->consumer WITHOUT draining vmcnt:
// writer-side ds ops complete (lgkmcnt(0)), then s_barrier. The global
// out-store stays fire-and-forget (no vmcnt(0) on the critical path).
#define LDS_BARRIER() do {                                   \
    asm volatile("s_waitcnt lgkmcnt(0)" ::: "memory");       \
    __builtin_amdgcn_s_barrier();                            \
    asm volatile("" ::: "memory");                           \
} while (0)

// ---------------------------------------------------------------------------
// Kernel 1: masked-mean embedding bag + step mask (unchanged)
// ---------------------------------------------------------------------------
__global__ __launch_bounds__(256) void emb_mean_kernel(
    const int* __restrict__ ids_g, const float* __restrict__ emb,
    float* __restrict__ x, float* __restrict__ mask)
{
    int grp  = blockIdx.x * 8 + (threadIdx.x >> 5);
    int lane = threadIdx.x & 31;
    if (grp >= BATCH * SEQ) return;
    const int* ids = ids_g + (size_t)grp * TOK;
    float acc = 0.f;
    int cnt = 0;
    #pragma unroll
    for (int t = 0; t < TOK; t++) {
        int id = ids[t];
        if (id != 0) {
            cnt++;
            if (lane < EMB) acc += emb[(size_t)id * EMB + lane];
        }
    }
    if (lane < EMB)
        x[(size_t)grp * EMB + lane] = cnt ? acc / (float)cnt : 0.f;
    if (lane == 0)
        mask[grp] = (ids[0] != 0) ? 1.f : 0.f;
}

// ---------------------------------------------------------------------------
// Kernel 2: GRU scan — THREE WAVES per (batch, direction), gate-split.
//   wave 0 -> z gate, wave 1 -> r gate, wave 2 -> h gate + combine.
// Round-1 post-mortem: float Ug[64]/Wg[25] ARRAYS were demoted to scratch
// (VGPR_Count=60!) -> ~89 L2-latency reloads per step (the asm "memory"
// clobbers forbid caching across barriers). Fix: NAMED SCALARS u0..u63 /
// w0..w24 — SSA values the allocator cannot demote. ~125 regs demanded,
// cap at __launch_bounds__(192,3) is ~170.
// Also: hs / xs rows read as broadcast float4 (ds_read_b128) to cut DS-pipe
// issue 4x; xs rows padded to stride 28 floats for 16B alignment.
// ---------------------------------------------------------------------------

#define U_LIST(M) \
  M(0)  M(1)  M(2)  M(3)  M(4)  M(5)  M(6)  M(7)  \
  M(8)  M(9)  M(10) M(11) M(12) M(13) M(14) M(15) \
  M(16) M(17) M(18) M(19) M(20) M(21) M(22) M(23) \
  M(24) M(25) M(26) M(27) M(28) M(29) M(30) M(31) \
  M(32) M(33) M(34) M(35) M(36) M(37) M(38) M(39) \
  M(40) M(41) M(42) M(43) M(44) M(45) M(46) M(47) \
  M(48) M(49) M(50) M(51) M(52) M(53) M(54) M(55) \
  M(56) M(57) M(58) M(59) M(60) M(61) M(62) M(63)

#define W_LIST(M) \
  M(0)  M(1)  M(2)  M(3)  M(4)  M(5)  M(6)  M(7)  \
  M(8)  M(9)  M(10) M(11) M(12) M(13) M(14) M(15) \
  M(16) M(17) M(18) M(19) M(20) M(21) M(22) M(23) M(24)

#define DECL_U(i) const float u##i = U[(i) * G3 + col];
#define DECL_W(i) const float w##i = W[(i) * G3 + col];

// one float4 broadcast read of hs, 4 fmas
#define REC4(q, i0, i1, i2, i3) {                 \
    const float4 hv = hs4[q];                     \
    a0 = fmaf(hv.x, u##i0, a0);                   \
    a1 = fmaf(hv.y, u##i1, a1);                   \
    a2 = fmaf(hv.z, u##i2, a2);                   \
    a3 = fmaf(hv.w, u##i3, a3); }

#define X4(q, i0, i1, i2, i3) {                   \
    const float4 xv = xr4[q];                     \
    p0 = fmaf(xv.x, w##i0, p0);                   \
    p1 = fmaf(xv.y, w##i1, p1);                   \
    p2 = fmaf(xv.z, w##i2, p2);                   \
    p3 = fmaf(xv.w, w##i3, p3); }

// x-projection of row XR (float* into xs, stride-XPAD row, 16B aligned)
#define XPROJ(P, XR) do {                                         \
    const float4* xr4 = (const float4*)(XR);                      \
    float p0 = bx, p1 = 0.f, p2 = 0.f, p3 = 0.f;                  \
    X4(0, 0, 1, 2, 3)   X4(1, 4, 5, 6, 7)   X4(2, 8, 9, 10, 11)  \
    X4(3, 12, 13, 14, 15) X4(4, 16, 17, 18, 19) X4(5, 20, 21, 22, 23) \
    p0 = fmaf((XR)[24], w24, p0);                                 \
    P = (p0 + p1) + (p2 + p3);                                    \
} while (0)

__global__ __launch_bounds__(192, 3) void gru_kernel(
    const float* __restrict__ xg, const float* __restrict__ maskg,
    const float* __restrict__ W_f, const float* __restrict__ U_f, const float* __restrict__ b_f,
    const float* __restrict__ W_b, const float* __restrict__ U_b, const float* __restrict__ b_b,
    float* __restrict__ outg, float* __restrict__ hT)
{
    const int bidx = blockIdx.x;
    const int dir  = bidx >> 9;        // 0 = forward, 1 = backward
    const int b    = bidx & 511;
    const int tid  = threadIdx.x;
    const int w    = tid >> 6;         // gate index: 0=z, 1=r, 2=h
    const int j    = tid & 63;         // hidden column

    const float* W    = dir ? W_b : W_f;
    const float* U    = dir ? U_b : U_f;
    const float* bias = dir ? b_b : b_f;

    const int col = w * HID + j;

    // per-lane weight column for THIS gate, as named scalars (forced VGPRs)
    U_LIST(DECL_U)
    W_LIST(DECL_W)
    const float bx = bias[col];        // input-projection bias
    const float br = bias[G3 + col];   // recurrent bias

    __shared__ __align__(16) float xs[SEQ * XPAD];   // 22.4 KB, padded rows
    __shared__ float ms[SEQ];
    __shared__ __align__(16) float hs[HID];
    __shared__ float zs[HID];
    __shared__ float rs[HID];

    // cooperative staging (coalesced global reads, padded LDS rows)
    {
        for (int i = tid; i < SEQ * EMB; i += 192) {
            int s = i / EMB;
            int e = i - s * EMB;
            xs[s * XPAD + e] = xg[(size_t)b * (SEQ * EMB) + i];
        }
        for (int i = tid; i < SEQ; i += 192) ms[i] = maskg[(size_t)b * SEQ + i];
        if (tid < HID) hs[tid] = 0.f;
    }
    __syncthreads();   // staging barrier (vmcnt drain fine, once)

    const float4* hs4 = (const float4*)hs;
    float h = 0.f;     // running hidden state, live only in wave 2
    float* obase = outg + (size_t)b * SEQ * (2 * HID) + dir * HID + j;

    // software-pipelined x-projection for step 0
    float p;
    {
        const int s0 = dir ? (SEQ - 1) : 0;
        XPROJ(p, xs + s0 * XPAD);
    }

    for (int step = 0; step < SEQ; step++) {
        const int s = dir ? (SEQ - 1 - step) : step;

        // recurrent dot: a = br + hs . u   (broadcast b128 reads, reg weights)
        float a0 = br, a1 = 0.f, a2 = 0.f, a3 = 0.f;
        REC4(0,  0,  1,  2,  3)   REC4(1,  4,  5,  6,  7)
        REC4(2,  8,  9, 10, 11)   REC4(3, 12, 13, 14, 15)
        REC4(4, 16, 17, 18, 19)   REC4(5, 20, 21, 22, 23)
        REC4(6, 24, 25, 26, 27)   REC4(7, 28, 29, 30, 31)
        REC4(8, 32, 33, 34, 35)   REC4(9, 36, 37, 38, 39)
        REC4(10, 40, 41, 42, 43)  REC4(11, 44, 45, 46, 47)
        REC4(12, 48, 49, 50, 51)  REC4(13, 52, 53, 54, 55)
        REC4(14, 56, 57, 58, 59)  REC4(15, 60, 61, 62, 63)
        const float a = (a0 + a1) + (a2 + a3);

        if (w == 0)      zs[j] = fast_sigmoid(p + a);
        else if (w == 1) rs[j] = fast_sigmoid(p + a);

        LDS_BARRIER();   // A: zs/rs visible to wave 2

        if (w == 2) {
            float r  = rs[j];
            float z  = zs[j];
            float hh = fast_tanh(p + r * a);        // p = xh-part, a = rec-part
            float hn = z * h + (1.f - z) * hh;
            hn = (ms[s] != 0.f) ? hn : h;
            h = hn;
            hs[j] = hn;
            obase[(size_t)s * (2 * HID)] = hn;      // fire-and-forget
        }

        // x-projection for the NEXT step (h-independent): overlaps wave-2's
        // combine latency and waves 0/1's barrier wait.
        {
            const int sn  = dir ? (SEQ - 2 - step) : (step + 1);
            const int snc = (step + 1 < SEQ) ? sn : s;   // clamp (unused on last iter)
            XPROJ(p, xs + snc * XPAD);
        }

        LDS_BARRIER();   // B: new hs visible to all waves
    }
    if (w == 2 && dir == 0) hT[(size_t)b * HID + j] = h;
}

// ---------------------------------------------------------------------------
// Kernel 3: attention pooling (unchanged). One block (256 thr) per batch.
// ---------------------------------------------------------------------------
__global__ __launch_bounds__(256) void attn_kernel(
    const float* __restrict__ outg, const float* __restrict__ maskg,
    const float* __restrict__ hT,
    const float* __restrict__ W_k, const float* __restrict__ b_k,
    const float* __restrict__ W_q, const float* __restrict__ b_q,
    const float* __restrict__ W_e, const float* __restrict__ b_e,
    float* __restrict__ ctx)
{
    const int b   = blockIdx.x;
    const int tid = threadIdx.x;

    __shared__ float Wks[2 * HID * HID];   // 128x64 = 32 KB
    __shared__ float qs[HID];
    __shared__ float es[SEQ];

    for (int i = tid; i < 2 * HID * HID; i += 256) Wks[i] = W_k[i];
    if (tid < HID) {
        float q = b_q[tid];
        const float* hrow = hT + (size_t)b * HID;
        #pragma unroll 8
        for (int i = 0; i < HID; i++) q = fmaf(hrow[i], W_q[i * HID + tid], q);
        qs[tid] = q;
    }
    __syncthreads();

    const int wave = tid >> 6;
    const int lane = tid & 63;
    const float bk = b_k[lane];
    const float we = W_e[lane];
    const float be = b_e[0];

    // phase 1: scores e[s]; each wave takes every 4th s
    for (int s = wave; s < SEQ; s += 4) {
        const float* orow = outg + ((size_t)b * SEQ + s) * (2 * HID);
        float a0 = 0.f, a1 = 0.f, a2 = 0.f, a3 = 0.f;
        #pragma unroll
        for (int i = 0; i < 2 * HID; i += 4) {
            a0 = fmaf(orow[i + 0], Wks[(i + 0) * HID + lane], a0);
            a1 = fmaf(orow[i + 1], Wks[(i + 1) * HID + lane], a1);
            a2 = fmaf(orow[i + 2], Wks[(i + 2) * HID + lane], a2);
            a3 = fmaf(orow[i + 3], Wks[(i + 3) * HID + lane], a3);
        }
        float t = tanhf(((a0 + a1) + (a2 + a3)) + bk + qs[lane]) * we;
        #pragma unroll
        for (int off = 32; off > 0; off >>= 1) t += __shfl_down(t, off);
        if (lane == 0) {
            float pen = (maskg[(size_t)b * SEQ + s] != 0.f) ? 0.f : -1e9f;
            es[s] = t + be + pen;
        }
    }
    __syncthreads();

    // phase 2: softmax over the 200 scores (single wave)
    if (tid < 64) {
        float mx = -1e30f;
        for (int s2 = tid; s2 < SEQ; s2 += 64) mx = fmaxf(mx, es[s2]);
        #pragma unroll
        for (int off = 32; off > 0; off >>= 1) mx = fmaxf(mx, __shfl_xor(mx, off));
        float sum = 0.f;
        for (int s2 = tid; s2 < SEQ; s2 += 64) {
            float w = expf(es[s2] - mx);
            es[s2] = w;
            sum += w;
        }
        #pragma unroll
        for (int off = 32; off > 0; off >>= 1) sum += __shfl_xor(sum, off);
        float inv = 1.f / sum;
        for (int s2 = tid; s2 < SEQ; s2 += 64) es[s2] *= inv;
    }
    __syncthreads();

    // phase 3: context[j] = sum_s w[s] * out[b,s,j]
    if (tid < 2 * HID) {
        const int jj = tid;
        float a0 = 0.f, a1 = 0.f;
        for (int s2 = 0; s2 < SEQ; s2 += 2) {
            a0 = fmaf(es[s2],     outg[((size_t)b * SEQ + s2)     * (2 * HID) + jj], a0);
            a1 = fmaf(es[s2 + 1], outg[((size_t)b * SEQ + s2 + 1) * (2 * HID) + jj], a1);
        }
        ctx[(size_t)b * (2 * HID) + jj] = a0 + a1;
    }
}

// ---------------------------------------------------------------------------
extern "C" void kernel_launch(void* const* d_in, const int* in_sizes, int n_in,
                              void* d_out, int out_size, void* d_ws, size_t ws_size,
                              hipStream_t stream) {
    const int*   ids = (const int*)  d_in[0];
    const float* emb = (const float*)d_in[1];
    const float* W_f = (const float*)d_in[2];
    const float* U_f = (const float*)d_in[3];
    const float* b_f = (const float*)d_in[4];
    const float* W_b = (const float*)d_in[5];
    const float* U_b = (const float*)d_in[6];
    const float* b_b = (const float*)d_in[7];
    const float* W_k = (const float*)d_in[8];
    const float* b_k = (const float*)d_in[9];
    const float* W_q = (const float*)d_in[10];
    const float* b_q = (const float*)d_in[11];
    const float* W_e = (const float*)d_in[12];
    const float* b_e = (const float*)d_in[13];

    float* ws   = (float*)d_ws;
    // workspace layout (floats):
    //   x    : [0, 2'560'000)                 (B*S*E)
    //   mask : [2'560'000, 2'662'400)         (B*S)
    //   out  : [2'662'400, 15'769'600)        (B*S*2H)
    //   hT   : [15'769'600, 15'802'368)       (B*H)
    float* x    = ws;
    float* mask = ws + 2560000;
    float* out  = ws + 2662400;
    float* hT   = ws + 15769600;

    emb_mean_kernel<<<(BATCH * SEQ) / 8, 256, 0, stream>>>(ids, emb, x, mask);
    gru_kernel<<<1024, 192, 0, stream>>>(x, mask, W_f, U_f, b_f,
                                         W_b, U_b, b_b, out, hT);
    attn_kernel<<<BATCH, 256, 0, stream>>>(out, mask, hT, W_k, b_k,
                                           W_q, b_q, W_e, b_e, (float*)d_out);
}